// Round 3
// baseline (2478.973 us; speedup 1.0000x reference)
//
#include <hip/hip_runtime.h>

// Problem: B=8, N=4096, D=256, K=4096; T = B*N = 32768 tokens.
// argmax_k dist == argmin_k t2, t2 = fl(fl(x_sq - 2*dot_k) + e_sq_k), ties -> lowest k.
// Numerics (validated round 2, absmax 0.0): numpy-pairwise sumsq, sequential-over-d
// fmaf dot accumulation, exact t1/t2 rounding sequence. All preserved bit-identically.

#define DDIM 256
#define BM 128        // tokens per block
#define BN 128        // codes per k-tile
#define BK 32         // D chunk
#define TM 8          // tokens per thread
#define TN 4          // codes per thread
#define KSPLIT 2      // grid = (T/BM)*KSPLIT = 512 blocks = 2/CU
#define NTHREADS 512  // (BM/TM)*(BN/TN) = 16*32

// word-level XOR swizzle (4-aligned, <32) spreading bank-quads across rows
__device__ __forceinline__ int swz(int m) {
    return ((m & 7) ^ ((m >> 3) & 7)) << 2;
}

#define GLOAD16(g, l) __builtin_amdgcn_global_load_lds(                      \
    (const __attribute__((address_space(1))) void*)(g),                      \
    (__attribute__((address_space(3))) void*)(l), 16, 0, 0)

// ---- kernel 1: row sum-of-squares replicating numpy pairwise_sum(n=256) ----
__global__ __launch_bounds__(256) void sumsq_np_kernel(const float* __restrict__ in,
                                                       float* __restrict__ out) {
    const int tid = threadIdx.x;
    const int row = blockIdx.x * 16 + (tid >> 4);
    const int lane16 = tid & 15;
    const int j = lane16 & 7;
    const int half = lane16 >> 3;
    const float* p = in + (size_t)row * DDIM + half * 128 + j;

    float v0 = p[0];
    float pr = v0 * v0;
    asm volatile("" : "+v"(pr));      // forbid FMA contraction: round product
    float s = pr;
    #pragma unroll
    for (int k = 1; k < 16; k++) {
        float v = p[8 * k];
        float q = v * v;
        asm volatile("" : "+v"(q));
        s += q;                       // sequential adds, ascending k (numpy order)
    }
    s += __shfl_xor(s, 1);
    s += __shfl_xor(s, 2);
    s += __shfl_xor(s, 4);
    s += __shfl_xor(s, 8);
    if (lane16 == 0) out[row] = s;
}

// ---- kernel 2: swizzled-LDS fp32 matmul + running argmin of t2 ----
__global__ __launch_bounds__(NTHREADS, 4)
void argmax_kernel(const float* __restrict__ x,
                   const float* __restrict__ embed,
                   const float* __restrict__ xsq,
                   const float* __restrict__ esq,
                   float* __restrict__ pval,
                   int* __restrict__ pidx,
                   int T, int K) {
    // lds words [0,4096): x-tile (m<128 rows x 32 kk, swizzled)
    // lds words [4096,8192): e-tile
    __shared__ __align__(16) float lds[8192];

    const int tid = threadIdx.x;
    const int split = blockIdx.x & (KSPLIT - 1);
    const int tile  = blockIdx.x >> 1;           // KSPLIT == 2
    const int tm0 = tile * BM;
    const int k0  = split * (K / KSPLIT);        // 0 or 2048

    const int L  = tid & 63;       // lane
    const int W  = tid >> 6;       // wave 0..7
    const int sr = L >> 3;         // 0..7 sub-row
    const int kx = (L & 7) << 2;   // 0..28

    const int c = tid & 31;        // code-group 0..31 (TN=4 codes)
    const int r = tid >> 5;        // token-group 0..15 (TM=8 tokens)

    // per-thread LDS fragment bases
    int abase[TM], axor[TM], bbase[TN], bxor[TN];
    #pragma unroll
    for (int i = 0; i < TM; i++) { int m = r * TM + i; abase[i] = m * 32; axor[i] = swz(m); }
    #pragma unroll
    for (int j = 0; j < TN; j++) { int n = c * TN + j; bbase[j] = 4096 + n * 32; bxor[j] = swz(n); }

    float xq[TM];
    #pragma unroll
    for (int i = 0; i < TM; i++) xq[i] = xsq[tm0 + r * TM + i];

    float best_val[TM];
    int   best_idx[TM];
    #pragma unroll
    for (int i = 0; i < TM; i++) { best_val[i] = INFINITY; best_idx[i] = 0; }

    for (int kt = 0; kt < K / KSPLIT; kt += BN) {
        float acc[TM][TN];
        #pragma unroll
        for (int i = 0; i < TM; i++)
            #pragma unroll
            for (int j = 0; j < TN; j++) acc[i][j] = 0.0f;

        for (int d0 = 0; d0 < DDIM; d0 += BK) {
            __syncthreads();   // previous chunk's readers done
            // stage both tiles: pre-swizzled global source, linear LDS dest.
            // LDS word = m*32 + kx holds global[m][kx ^ swz(m)].
            #pragma unroll
            for (int rd = 0; rd < 2; rd++) {
                const int m  = rd * 64 + W * 8 + sr;
                const int kk = kx ^ swz(m);
                GLOAD16(x + (size_t)(tm0 + m) * DDIM + d0 + kk,
                        &lds[rd * 2048 + W * 256]);
                GLOAD16(embed + (size_t)(k0 + kt + m) * DDIM + d0 + kk,
                        &lds[4096 + rd * 2048 + W * 256]);
            }
            __syncthreads();   // compiler drains vmcnt(0) before barrier

            #pragma unroll
            for (int kk0 = 0; kk0 < BK; kk0 += 4) {
                float4 b[TN];
                #pragma unroll
                for (int j = 0; j < TN; j++)
                    b[j] = *(const float4*)&lds[bbase[j] + (kk0 ^ bxor[j])];
                #pragma unroll
                for (int i = 0; i < TM; i++) {
                    const float4 a = *(const float4*)&lds[abase[i] + (kk0 ^ axor[i])];
                    #pragma unroll
                    for (int j = 0; j < TN; j++) {
                        float t = acc[i][j];          // sequential over d: bit-identical
                        t = fmaf(a.x, b[j].x, t);     // to the round-2 kernel
                        t = fmaf(a.y, b[j].y, t);
                        t = fmaf(a.z, b[j].z, t);
                        t = fmaf(a.w, b[j].w, t);
                        acc[i][j] = t;
                    }
                }
            }
        }

        // epilogue: t2 = fl(fl(x_sq - 2*dot) + e_sq); running argmin, ties->lowest k
        #pragma unroll
        for (int j = 0; j < TN; j++) {
            const int code = k0 + kt + c * TN + j;
            const float eq = esq[code];
            #pragma unroll
            for (int i = 0; i < TM; i++) {
                const float t1 = xq[i] - 2.0f * acc[i][j];
                const float t2 = t1 + eq;
                if (t2 < best_val[i]) { best_val[i] = t2; best_idx[i] = code; }
            }
        }
    }

    // reduce across the 32 code-groups (lanes 0..31 of each half-wave)
    #pragma unroll
    for (int i = 0; i < TM; i++) {
        float v = best_val[i];
        int   ix = best_idx[i];
        #pragma unroll
        for (int off = 1; off < 32; off <<= 1) {
            const float ov = __shfl_xor(v, off);
            const int   oi = __shfl_xor(ix, off);
            if (ov < v || (ov == v && oi < ix)) { v = ov; ix = oi; }
        }
        if (c == 0) {
            pval[split * T + tm0 + r * TM + i] = v;
            pidx[split * T + tm0 + r * TM + i] = ix;
        }
    }
}

// ---- kernel 3: merge K-split partials, gather quantize, write indices ----
__global__ __launch_bounds__(256) void merge_gather_kernel(const float* __restrict__ embed,
                                                           const float* __restrict__ pval,
                                                           const int* __restrict__ pidx,
                                                           float* __restrict__ quant,
                                                           float* __restrict__ out_ind,
                                                           int T) {
    const int wave = threadIdx.x >> 6;
    const int lane = threadIdx.x & 63;
    const int t = blockIdx.x * 4 + wave;
    const float v0 = pval[t], v1 = pval[T + t];
    const int   i0 = pidx[t], i1 = pidx[T + t];
    // split-0 indices are always lower; strict < keeps split 0 on ties
    const int k = (v1 < v0) ? i1 : i0;
    float4 v = reinterpret_cast<const float4*>(embed + (size_t)k * DDIM)[lane];
    reinterpret_cast<float4*>(quant + (size_t)t * DDIM)[lane] = v;
    if (lane == 0) out_ind[t] = (float)k;
}

extern "C" void kernel_launch(void* const* d_in, const int* in_sizes, int n_in,
                              void* d_out, int out_size, void* d_ws, size_t ws_size,
                              hipStream_t stream) {
    const float* x     = (const float*)d_in[0];
    const float* embed = (const float*)d_in[1];
    // d_in[2] = node_mask: does not affect the two outputs.

    const int T = in_sizes[0] / DDIM;   // 32768
    const int K = in_sizes[1] / DDIM;   // 4096

    float* xsq  = (float*)d_ws;                    // T floats
    float* esq  = xsq + T;                         // K floats
    float* pval = esq + K;                         // KSPLIT*T floats
    int*   pidx = (int*)(pval + KSPLIT * T);       // KSPLIT*T ints

    float* quant   = (float*)d_out;
    float* out_ind = (float*)d_out + (size_t)T * DDIM;

    sumsq_np_kernel<<<T / 16, 256, 0, stream>>>(x, xsq);
    sumsq_np_kernel<<<K / 16, 256, 0, stream>>>(embed, esq);
    argmax_kernel<<<(T / BM) * KSPLIT, NTHREADS, 0, stream>>>(x, embed, xsq, esq,
                                                              pval, pidx, T, K);
    merge_gather_kernel<<<T / 4, 256, 0, stream>>>(embed, pval, pidx, quant, out_ind, T);
}

// Round 4
// 1119.907 us; speedup vs baseline: 2.2136x; 2.2136x over previous
//
#include <hip/hip_runtime.h>

// Problem: B=8, N=4096, D=256, K=4096; T = B*N = 32768 tokens.
// argmax_k dist == argmin_k t2, t2 = fl(fl(x_sq - 2*dot_k) + e_sq_k), ties -> lowest k.
// Numerics (validated rounds 2-3, absmax 0.0): numpy-pairwise sumsq, float4-grouped
// sequential fmaf dot accumulation (x,y,z,w then ascending kk0/d0), exact t1/t2.

#define DDIM 256
#define BM 64         // tokens per block
#define BN 128        // codes per k-tile
#define BK 32         // D chunk
#define TM 4          // tokens per thread  (r = tid>>4: 16 groups)
#define TN 8          // codes per thread   (c = tid&15: 16 groups)
#define KSPLIT 2      // grid = (T/BM)*KSPLIT = 1024 blocks = 4/CU exactly
#define NTHREADS 256

// LDS layout: row-major [row][32 words], column 4-word-chunk XOR-swizzled by
// row-group: LDS[row*32 + w] = src[row][w ^ ((row>>3 & 7)<<2)].
// B-read (16 lanes, rows 8c+j): bank base = kk0 ^ ((c&7)<<2) -> 8 distinct
// quads, 2 lanes each = free. A-read: 4 rows in ONE 8-group -> uniform XOR.

#define GLOAD16(g, l) __builtin_amdgcn_global_load_lds(                      \
    (const __attribute__((address_space(1))) void*)(g),                      \
    (__attribute__((address_space(3))) void*)(l), 16, 0, 0)

// ---- kernel 1: row sum-of-squares replicating numpy pairwise_sum(n=256) ----
__global__ __launch_bounds__(256) void sumsq_np_kernel(const float* __restrict__ in,
                                                       float* __restrict__ out) {
    const int tid = threadIdx.x;
    const int row = blockIdx.x * 16 + (tid >> 4);
    const int lane16 = tid & 15;
    const int j = lane16 & 7;
    const int half = lane16 >> 3;
    const float* p = in + (size_t)row * DDIM + half * 128 + j;

    float v0 = p[0];
    float pr = v0 * v0;
    asm volatile("" : "+v"(pr));      // forbid FMA contraction: round product
    float s = pr;
    #pragma unroll
    for (int k = 1; k < 16; k++) {
        float v = p[8 * k];
        float q = v * v;
        asm volatile("" : "+v"(q));
        s += q;                       // sequential adds, ascending k (numpy order)
    }
    s += __shfl_xor(s, 1);
    s += __shfl_xor(s, 2);
    s += __shfl_xor(s, 4);
    s += __shfl_xor(s, 8);
    if (lane16 == 0) out[row] = s;
}

// ---- kernel 2: swizzled-LDS fp32 matmul + running argmin of t2 ----
__global__ __launch_bounds__(NTHREADS)
void argmax_kernel(const float* __restrict__ x,
                   const float* __restrict__ embed,
                   const float* __restrict__ xsq,
                   const float* __restrict__ esq,
                   float* __restrict__ pval,
                   int* __restrict__ pidx,
                   int T, int K) {
    __shared__ __align__(16) float x_lds[BM * BK];   // 8 KB
    __shared__ __align__(16) float e_lds[BN * BK];   // 16 KB

    const int tid = threadIdx.x;
    const int split = blockIdx.x & (KSPLIT - 1);
    const int tile  = blockIdx.x >> 1;               // KSPLIT == 2
    const int tm0 = tile * BM;
    const int k0  = split * (K / KSPLIT);            // 0 or 2048

    const int L = tid & 63;        // lane
    const int W = tid >> 6;        // wave 0..3

    const int c = tid & 15;        // code-group (TN=8 codes: rows 8c..8c+7)
    const int r = tid >> 4;        // token-group (TM=4 tokens: rows 4r..4r+3)

    const int swzA = ((r >> 1) & 7) << 2;   // 4 token rows share 8-group r>>1
    const int swzB = (c & 7) << 2;          // 8 code rows are exactly group c

    // staging source offsets (floats), constant per thread; 8-row groups per instr
    int xoff[2], eoff[4];
    #pragma unroll
    for (int rd = 0; rd < 2; rd++) {
        const int m0 = W * 16 + rd * 8;
        const int col = (((L & 7) << 2)) ^ ((((m0 >> 3) & 7)) << 2);
        xoff[rd] = (m0 + (L >> 3)) * DDIM + col;
    }
    #pragma unroll
    for (int re = 0; re < 4; re++) {
        const int m0 = W * 32 + re * 8;
        const int col = (((L & 7) << 2)) ^ ((((m0 >> 3) & 7)) << 2);
        eoff[re] = (m0 + (L >> 3)) * DDIM + col;
    }

    const float* xbase = x + (size_t)tm0 * DDIM;

    float xq[TM];
    #pragma unroll
    for (int i = 0; i < TM; i++) xq[i] = xsq[tm0 + r * TM + i];

    float best_val[TM];
    int   best_idx[TM];
    #pragma unroll
    for (int i = 0; i < TM; i++) { best_val[i] = INFINITY; best_idx[i] = 0; }

    for (int kt = 0; kt < K / KSPLIT; kt += BN) {
        const float* ebase = embed + (size_t)(k0 + kt) * DDIM;

        float acc[TM][TN];
        #pragma unroll
        for (int i = 0; i < TM; i++)
            #pragma unroll
            for (int j = 0; j < TN; j++) acc[i][j] = 0.0f;

        for (int d0 = 0; d0 < DDIM; d0 += BK) {
            __syncthreads();   // previous chunk's readers done
            #pragma unroll
            for (int rd = 0; rd < 2; rd++)
                GLOAD16(xbase + d0 + xoff[rd], &x_lds[(W * 16 + rd * 8) * BK]);
            #pragma unroll
            for (int re = 0; re < 4; re++)
                GLOAD16(ebase + d0 + eoff[re], &e_lds[(W * 32 + re * 8) * BK]);
            __syncthreads();   // compiler drains vmcnt(0) before barrier

            #pragma unroll
            for (int kk0 = 0; kk0 < BK; kk0 += 4) {
                const float* bp = &e_lds[(c * TN) * BK + (kk0 ^ swzB)];
                float4 b[TN];
                #pragma unroll
                for (int j = 0; j < TN; j++)
                    b[j] = *(const float4*)(bp + j * BK);
                const float* ap = &x_lds[(r * TM) * BK + (kk0 ^ swzA)];
                #pragma unroll
                for (int i = 0; i < TM; i++) {
                    const float4 a = *(const float4*)(ap + i * BK);
                    #pragma unroll
                    for (int j = 0; j < TN; j++) {
                        float t = acc[i][j];          // per-acc chain: x,y,z,w then
                        t = fmaf(a.x, b[j].x, t);     // ascending kk0, d0 — bit-
                        t = fmaf(a.y, b[j].y, t);     // identical to rounds 2/3
                        t = fmaf(a.z, b[j].z, t);
                        t = fmaf(a.w, b[j].w, t);
                        acc[i][j] = t;
                    }
                }
            }
        }

        // epilogue: t2 = fl(fl(x_sq - 2*dot) + e_sq); running argmin, ties->lowest k
        #pragma unroll
        for (int j = 0; j < TN; j++) {
            const int code = k0 + kt + c * TN + j;
            const float eq = esq[code];
            #pragma unroll
            for (int i = 0; i < TM; i++) {
                const float t1 = xq[i] - 2.0f * acc[i][j];
                const float t2 = t1 + eq;
                if (t2 < best_val[i]) { best_val[i] = t2; best_idx[i] = code; }
            }
        }
    }

    // reduce across the 16 c-groups (contiguous 16 lanes share r); ties->lower idx
    #pragma unroll
    for (int i = 0; i < TM; i++) {
        float v = best_val[i];
        int   ix = best_idx[i];
        #pragma unroll
        for (int off = 1; off < 16; off <<= 1) {
            const float ov = __shfl_xor(v, off);
            const int   oi = __shfl_xor(ix, off);
            if (ov < v || (ov == v && oi < ix)) { v = ov; ix = oi; }
        }
        if (c == 0) {
            pval[split * T + tm0 + r * TM + i] = v;
            pidx[split * T + tm0 + r * TM + i] = ix;
        }
    }
}

// ---- kernel 3: merge K-split partials, gather quantize, write indices ----
__global__ __launch_bounds__(256) void merge_gather_kernel(const float* __restrict__ embed,
                                                           const float* __restrict__ pval,
                                                           const int* __restrict__ pidx,
                                                           float* __restrict__ quant,
                                                           float* __restrict__ out_ind,
                                                           int T) {
    const int wave = threadIdx.x >> 6;
    const int lane = threadIdx.x & 63;
    const int t = blockIdx.x * 4 + wave;
    const float v0 = pval[t], v1 = pval[T + t];
    const int   i0 = pidx[t], i1 = pidx[T + t];
    // split-0 indices are always lower; strict < keeps split 0 on ties
    const int k = (v1 < v0) ? i1 : i0;
    float4 v = reinterpret_cast<const float4*>(embed + (size_t)k * DDIM)[lane];
    reinterpret_cast<float4*>(quant + (size_t)t * DDIM)[lane] = v;
    if (lane == 0) out_ind[t] = (float)k;
}

extern "C" void kernel_launch(void* const* d_in, const int* in_sizes, int n_in,
                              void* d_out, int out_size, void* d_ws, size_t ws_size,
                              hipStream_t stream) {
    const float* x     = (const float*)d_in[0];
    const float* embed = (const float*)d_in[1];
    // d_in[2] = node_mask: does not affect the two outputs.

    const int T = in_sizes[0] / DDIM;   // 32768
    const int K = in_sizes[1] / DDIM;   // 4096

    float* xsq  = (float*)d_ws;                    // T floats
    float* esq  = xsq + T;                         // K floats
    float* pval = esq + K;                         // KSPLIT*T floats
    int*   pidx = (int*)(pval + KSPLIT * T);       // KSPLIT*T ints

    float* quant   = (float*)d_out;
    float* out_ind = (float*)d_out + (size_t)T * DDIM;

    sumsq_np_kernel<<<T / 16, 256, 0, stream>>>(x, xsq);
    sumsq_np_kernel<<<K / 16, 256, 0, stream>>>(embed, esq);
    argmax_kernel<<<(T / BM) * KSPLIT, NTHREADS, 0, stream>>>(x, embed, xsq, esq,
                                                              pval, pidx, T, K);
    merge_gather_kernel<<<T / 4, 256, 0, stream>>>(embed, pval, pidx, quant, out_ind, T);
}

// Round 5
// 930.989 us; speedup vs baseline: 2.6627x; 1.2029x over previous
//
#include <hip/hip_runtime.h>

// Problem: B=8, N=4096, D=256, K=4096; T = B*N = 32768 tokens.
// argmax_k dist == argmin_k t2, t2 = fl(fl(x_sq - 2*dot_k) + e_sq_k), ties -> lowest k.
// Numerics (validated rounds 2-4, absmax 0.0): numpy-pairwise sumsq, strictly
// ascending-d sequential fmaf chain per accumulator, exact t1/t2 rounding, ties
// resolved to lowest code index.

#define DDIM 256
#define BM 128        // tokens per block tile
#define BN 128        // codes per k-tile
#define BK 32         // D chunk
#define TM 8          // tokens per thread  (r = tid>>4: rows r*8..r*8+7)
#define TN 8          // codes per thread   (c = tid&15: rows c*8..c*8+7)
#define KSPLIT 4      // grid = (T/BM)*KSPLIT = 1024 blocks = 4/CU
#define NTHREADS 256

// LDS: row-major [row][32 words]; column chunk XOR-swizzled by row-group:
// LDS[row*32 + w] = src[row][w ^ (((row>>3)&7)<<2)].
// A-read (frag rows r*8+i, group == r): 4 unique addrs/wave, distinct quads,
// 16-lane broadcast -> conflict-free. B-read (rows c*8+j, group == c): 16 unique
// addrs, 8 quads, 2 addrs/quad = 2-way (free per m136).

#define GLOAD16(g, l) __builtin_amdgcn_global_load_lds(                      \
    (const __attribute__((address_space(1))) void*)(g),                      \
    (__attribute__((address_space(3))) void*)(l), 16, 0, 0)

// ---- kernel 1: row sum-of-squares replicating numpy pairwise_sum(n=256) ----
__global__ __launch_bounds__(256) void sumsq_np_kernel(const float* __restrict__ in,
                                                       float* __restrict__ out) {
    const int tid = threadIdx.x;
    const int row = blockIdx.x * 16 + (tid >> 4);
    const int lane16 = tid & 15;
    const int j = lane16 & 7;
    const int half = lane16 >> 3;
    const float* p = in + (size_t)row * DDIM + half * 128 + j;

    float v0 = p[0];
    float pr = v0 * v0;
    asm volatile("" : "+v"(pr));      // forbid FMA contraction: round product
    float s = pr;
    #pragma unroll
    for (int k = 1; k < 16; k++) {
        float v = p[8 * k];
        float q = v * v;
        asm volatile("" : "+v"(q));
        s += q;                       // sequential adds, ascending k (numpy order)
    }
    s += __shfl_xor(s, 1);
    s += __shfl_xor(s, 2);
    s += __shfl_xor(s, 4);
    s += __shfl_xor(s, 8);
    if (lane16 == 0) out[row] = s;
}

// ---- kernel 2: swizzled-LDS fp32 matmul (8x8/thread) + running argmin of t2 ----
__global__ __launch_bounds__(NTHREADS)
void argmax_kernel(const float* __restrict__ x,
                   const float* __restrict__ embed,
                   const float* __restrict__ xsq,
                   const float* __restrict__ esq,
                   float* __restrict__ pval,
                   int* __restrict__ pidx,
                   int T, int K) {
    __shared__ __align__(16) float lds[(BM + BN) * BK];   // 32 KB
    float* const x_lds = lds;
    float* const e_lds = lds + BM * BK;

    const int tid = threadIdx.x;
    const int split = blockIdx.x & (KSPLIT - 1);
    const int tile  = blockIdx.x >> 2;               // KSPLIT == 4
    const int tm0 = tile * BM;
    const int k0  = split * (K / KSPLIT);            // split * 1024

    const int L = tid & 63;        // lane
    const int W = tid >> 6;        // wave 0..3

    const int c = tid & 15;        // code-group: rows c*8 .. c*8+7
    const int r = tid >> 4;        // token-group: rows r*8 .. r*8+7

    // staging source offsets (floats) within a 128-row x 256-col panel;
    // instr g covers rows W*32+g*8 .. +7 (8 rows x 32 cols = 64 lanes x 16B)
    int soff[4];
    #pragma unroll
    for (int g = 0; g < 4; g++) {
        const int row = W * 32 + g * 8 + (L >> 3);
        const int col = ((L & 7) << 2) ^ (((W * 4 + g) & 7) << 2);
        soff[g] = row * DDIM + col;
    }

    // read bases: fragment rows are consecutive -> one addr + offset:j*128
    const int aSwz = (r & 7) << 4;                   // byte XOR, bits 4-6
    const int bSwz = (c & 7) << 4;
    const char* const aBase = (const char*)x_lds + r * 8 * (BK * 4);
    const char* const bBase = (const char*)e_lds + c * 8 * (BK * 4);

    float best_val[TM];
    int   best_idx[TM];
    #pragma unroll
    for (int i = 0; i < TM; i++) { best_val[i] = INFINITY; best_idx[i] = 0; }

    const float* const xpanel = x + (size_t)tm0 * DDIM;

    for (int kt = 0; kt < K / KSPLIT; kt += BN) {
        const float* const epanel = embed + (size_t)(k0 + kt) * DDIM;

        float acc[TM][TN];
        #pragma unroll
        for (int i = 0; i < TM; i++)
            #pragma unroll
            for (int j = 0; j < TN; j++) acc[i][j] = 0.0f;

        for (int d0 = 0; d0 < DDIM; d0 += BK) {
            __syncthreads();   // previous chunk's readers done
            #pragma unroll
            for (int g = 0; g < 4; g++) {
                GLOAD16(xpanel + d0 + soff[g], &x_lds[(W * 32 + g * 8) * BK]);
                GLOAD16(epanel + d0 + soff[g], &e_lds[(W * 32 + g * 8) * BK]);
            }
            __syncthreads();   // compiler drains vmcnt(0) before barrier

            #pragma unroll
            for (int kk0 = 0; kk0 < BK; kk0 += 4) {
                const char* ap = aBase + ((kk0 * 4) ^ aSwz);
                const char* bp = bBase + ((kk0 * 4) ^ bSwz);
                float4 b[TN];
                #pragma unroll
                for (int j = 0; j < TN; j++)
                    b[j] = *(const float4*)(bp + j * (BK * 4));
                #pragma unroll
                for (int i = 0; i < TM; i++) {
                    const float4 a = *(const float4*)(ap + i * (BK * 4));
                    #pragma unroll
                    for (int j = 0; j < TN; j++) {
                        float t = acc[i][j];          // per-acc chain: d,d+1,d+2,d+3
                        t = fmaf(a.x, b[j].x, t);     // then ascending kk0, d0 —
                        t = fmaf(a.y, b[j].y, t);     // bit-identical to rounds 2-4
                        t = fmaf(a.z, b[j].z, t);
                        t = fmaf(a.w, b[j].w, t);
                        acc[i][j] = t;
                    }
                }
            }
        }

        // epilogue: t2 = fl(fl(x_sq - 2*dot) + e_sq); running argmin, ties->lowest k
        float eq[TN];
        #pragma unroll
        for (int j = 0; j < TN; j++) eq[j] = esq[k0 + kt + c * TN + j];
        #pragma unroll
        for (int i = 0; i < TM; i++) {
            const float xq = xsq[tm0 + r * TM + i];
            #pragma unroll
            for (int j = 0; j < TN; j++) {           // j ascending: lowest code wins ties
                const int code = k0 + kt + c * TN + j;
                const float t1 = xq - 2.0f * acc[i][j];
                const float t2 = t1 + eq[j];
                if (t2 < best_val[i]) { best_val[i] = t2; best_idx[i] = code; }
            }
        }
    }

    // reduce across the 16 c-groups (contiguous 16 lanes share r); ties->lower idx
    #pragma unroll
    for (int i = 0; i < TM; i++) {
        float v = best_val[i];
        int   ix = best_idx[i];
        #pragma unroll
        for (int off = 1; off < 16; off <<= 1) {
            const float ov = __shfl_xor(v, off);
            const int   oi = __shfl_xor(ix, off);
            if (ov < v || (ov == v && oi < ix)) { v = ov; ix = oi; }
        }
        if (c == 0) {
            pval[split * T + tm0 + r * TM + i] = v;
            pidx[split * T + tm0 + r * TM + i] = ix;
        }
    }
}

// ---- kernel 3: merge K-split partials, gather quantize, write indices ----
__global__ __launch_bounds__(256) void merge_gather_kernel(const float* __restrict__ embed,
                                                           const float* __restrict__ pval,
                                                           const int* __restrict__ pidx,
                                                           float* __restrict__ quant,
                                                           float* __restrict__ out_ind,
                                                           int T) {
    const int wave = threadIdx.x >> 6;
    const int lane = threadIdx.x & 63;
    const int t = blockIdx.x * 4 + wave;
    // ascending-split scan with strict < keeps the lowest code index on ties
    float bv = pval[t];
    int   bi = pidx[t];
    #pragma unroll
    for (int s = 1; s < KSPLIT; s++) {
        const float v = pval[s * T + t];
        const int   ii = pidx[s * T + t];
        if (v < bv) { bv = v; bi = ii; }
    }
    float4 v = reinterpret_cast<const float4*>(embed + (size_t)bi * DDIM)[lane];
    reinterpret_cast<float4*>(quant + (size_t)t * DDIM)[lane] = v;
    if (lane == 0) out_ind[t] = (float)bi;
}

extern "C" void kernel_launch(void* const* d_in, const int* in_sizes, int n_in,
                              void* d_out, int out_size, void* d_ws, size_t ws_size,
                              hipStream_t stream) {
    const float* x     = (const float*)d_in[0];
    const float* embed = (const float*)d_in[1];
    // d_in[2] = node_mask: does not affect the two outputs.

    const int T = in_sizes[0] / DDIM;   // 32768
    const int K = in_sizes[1] / DDIM;   // 4096

    float* xsq  = (float*)d_ws;                    // T floats
    float* esq  = xsq + T;                         // K floats
    float* pval = esq + K;                         // KSPLIT*T floats
    int*   pidx = (int*)(pval + KSPLIT * T);       // KSPLIT*T ints

    float* quant   = (float*)d_out;
    float* out_ind = (float*)d_out + (size_t)T * DDIM;

    sumsq_np_kernel<<<T / 16, 256, 0, stream>>>(x, xsq);
    sumsq_np_kernel<<<K / 16, 256, 0, stream>>>(embed, esq);
    argmax_kernel<<<(T / BM) * KSPLIT, NTHREADS, 0, stream>>>(x, embed, xsq, esq,
                                                              pval, pidx, T, K);
    merge_gather_kernel<<<T / 4, 256, 0, stream>>>(embed, pval, pidx, quant, out_ind, T);
}

// Round 7
// 646.502 us; speedup vs baseline: 3.8344x; 1.4400x over previous
//
#include <hip/hip_runtime.h>

// B=8, N=4096, D=256, K=4096; T = 32768 tokens.
// argmax_k dist == argmin_k t2, t2 = fl(fl(x_sq - 2*dot_k) + e_sq_k), ties -> lowest k.
// Strategy: bf16x2 3-product MFMA screen (approx_t2, |err| <= ~1.5e-4) + per-token
// top-3 tracking; ambiguous tokens (top-2 gap < MU) rescored with the bit-exact
// numpy-matched chain validated in rounds 2-5 (absmax 0.0 three times).
// Round-6 bug fixed here: the two wc-waves cover disjoint code halves and their
// top-3 states are now merged through LDS instead of racing on the same slot.

#define TT 32768
#define KK 4096
#define DD 256
#define MU 2.5e-3f      // >> worst-case |approx_t2 - exact_t2| (~1.5e-4)
#define KSPLIT 2

typedef short bf16x8 __attribute__((ext_vector_type(8)));
typedef float f32x4 __attribute__((ext_vector_type(4)));

#define GLOAD16(g, l) __builtin_amdgcn_global_load_lds(                      \
    (const __attribute__((address_space(1))) void*)(g),                      \
    (__attribute__((address_space(3))) void*)(l), 16, 0, 0)

// RNE fp32 -> bf16 bits
__device__ __forceinline__ unsigned short bf16_rne(float f) {
    unsigned int u = __float_as_uint(f);
    unsigned int r = u + 0x7FFFu + ((u >> 16) & 1u);
    return (unsigned short)(r >> 16);
}

// sorted-triple merge: (m1,i1,m2,i2,m3) <- top3 of union with (n1,j1,n2,j2,n3).
// Value ties prefer lower index (i-slots); m3 is value-only.
__device__ __forceinline__ void comb(float& m1, int& i1, float& m2, int& i2, float& m3,
                                     float n1, int j1, float n2, int j2, float n3) {
    bool aw = (m1 < n1) || (m1 == n1 && i1 < j1);   // current head wins
    float loser = aw ? n1 : m1;  int loserI = aw ? j1 : i1;
    float w2 = aw ? m2 : n2;     int w2I = aw ? i2 : j2;
    float w3 = aw ? m3 : n3;
    float o2 = aw ? n2 : m2;
    float f1 = aw ? m1 : n1;     int f1I = aw ? i1 : j1;
    bool bw = (w2 < loser) || (w2 == loser && w2I < loserI);
    float f2 = bw ? w2 : loser;  int f2I = bw ? w2I : loserI;
    float f3 = bw ? fminf(w3, loser) : fminf(w2, o2);
    m1 = f1; i1 = f1I; m2 = f2; i2 = f2I; m3 = f3;
}

// ---- kernel 1: numpy-pairwise sumsq (bit-exact, validated) + bf16x2 split ----
__global__ __launch_bounds__(256) void prep_kernel(const float* __restrict__ in,
                                                   float* __restrict__ sq,
                                                   short* __restrict__ hi,
                                                   short* __restrict__ lo) {
    const int tid = threadIdx.x;
    const int row = blockIdx.x * 16 + (tid >> 4);
    const int lane16 = tid & 15;
    // phase 1: numpy pairwise sum-of-squares (n=256 -> 2 halves x 8 strided accs)
    {
        const int j = lane16 & 7;
        const int half = lane16 >> 3;
        const float* p = in + (size_t)row * DD + half * 128 + j;
        float v0 = p[0];
        float pr = v0 * v0;
        asm volatile("" : "+v"(pr));      // round product separately (no FMA fuse)
        float s = pr;
        #pragma unroll
        for (int k = 1; k < 16; k++) {
            float v = p[8 * k];
            float q = v * v;
            asm volatile("" : "+v"(q));
            s += q;
        }
        s += __shfl_xor(s, 1);
        s += __shfl_xor(s, 2);
        s += __shfl_xor(s, 4);
        s += __shfl_xor(s, 8);
        if (lane16 == 0) sq[row] = s;
    }
    // phase 2: exact 2-term bf16 split: v = hi + lo + r, |r| <= 2^-18 |v|
    {
        const int d0 = lane16 * 16;
        #pragma unroll
        for (int q = 0; q < 4; q++) {
            float4 v = *reinterpret_cast<const float4*>(in + (size_t)row * DD + d0 + q * 4);
            short4 h, l;
            float fv[4] = {v.x, v.y, v.z, v.w};
            unsigned short hb[4], lb[4];
            #pragma unroll
            for (int e = 0; e < 4; e++) {
                hb[e] = bf16_rne(fv[e]);
                float hf = __uint_as_float(((unsigned int)hb[e]) << 16);
                lb[e] = bf16_rne(fv[e] - hf);
            }
            h.x = (short)hb[0]; h.y = (short)hb[1]; h.z = (short)hb[2]; h.w = (short)hb[3];
            l.x = (short)lb[0]; l.y = (short)lb[1]; l.z = (short)lb[2]; l.w = (short)lb[3];
            *reinterpret_cast<short4*>(hi + (size_t)row * DD + d0 + q * 4) = h;
            *reinterpret_cast<short4*>(lo + (size_t)row * DD + d0 + q * 4) = l;
        }
    }
}

// ---- kernel 2: bf16x2 3-product MFMA screen, per-token top3(+top2 idx) ----
// 256 thr = 4 waves (2 token-halves x 2 code-halves). Block: 64 tokens x 128
// codes per ktile. Wave: 32 tokens x 64 codes, 16x16x32 MFMA, frags ai=0..1,
// bj=0..3. wc-halves merged through LDS at the end (round-6 fix).
__global__ __launch_bounds__(256)
void screen_kernel(const short* __restrict__ x_hi, const short* __restrict__ x_lo,
                   const short* __restrict__ e_hi, const short* __restrict__ e_lo,
                   const float* __restrict__ xsq, const float* __restrict__ esq,
                   float* __restrict__ sm1, int* __restrict__ si1,
                   float* __restrict__ sm2, int* __restrict__ si2,
                   float* __restrict__ sm3) {
    // shorts: A-hi [0,2048) 4 subtiles, A-lo [2048,4096),
    //         B-hi [4096,8192) 8 subtiles, B-lo [8192,12288). 24 KB.
    __shared__ __align__(16) short lds[12288];

    const int tid = threadIdx.x;
    const int split = blockIdx.x & (KSPLIT - 1);
    const int tile  = blockIdx.x >> 1;
    const int t0 = tile * 64;
    const int k0 = split * (KK / KSPLIT);

    const int l = tid & 63;
    const int w = tid >> 6;        // wave 0..3
    const int wr = w >> 1;         // token half (32 tokens)
    const int wc = w & 1;          // code half (64 codes)

    // staging: linear LDS dest (lane*16B); source column chunk-XOR-swizzled by
    // row so fragment ds_read_b128 lands 2-way max (free) instead of 8-way.
    const int srow = l >> 2;                              // row 0..15 in subtile
    const int scol = (((l & 3) ^ ((srow >> 1) & 3)) << 3);
    const short* sAh = x_hi + (size_t)(t0 + w * 16 + srow) * DD + scol;
    const short* sAl = x_lo + (size_t)(t0 + w * 16 + srow) * DD + scol;
    const size_t browg = (size_t)(k0 + w * 32 + srow) * DD + scol;
    const short* sB0h = e_hi + browg;
    const short* sB1h = e_hi + browg + 16 * DD;
    const short* sB0l = e_lo + browg;
    const short* sB1l = e_lo + browg + 16 * DD;
    short* const dAh  = &lds[w * 512];
    short* const dAl  = &lds[2048 + w * 512];
    short* const dB0h = &lds[4096 + (2 * w) * 512];
    short* const dB1h = &lds[4096 + (2 * w + 1) * 512];
    short* const dB0l = &lds[8192 + (2 * w) * 512];
    short* const dB1l = &lds[8192 + (2 * w + 1) * 512];

    // fragment reads: row fr = l&15, chunk (l>>4) re-swizzled -> data view is
    // exactly slot i <-> k = 8*(l>>4)+i (same mapping for A and B => dot exact).
    const int fr = l & 15;
    const int fq = (l >> 4) ^ ((fr >> 1) & 3);
    const int laneoff = fr * 32 + fq * 8;
    const short *fAh[2], *fAl[2], *fBh[4], *fBl[4];
    #pragma unroll
    for (int ai = 0; ai < 2; ai++) {
        fAh[ai] = &lds[(wr * 2 + ai) * 512 + laneoff];
        fAl[ai] = &lds[2048 + (wr * 2 + ai) * 512 + laneoff];
    }
    #pragma unroll
    for (int bj = 0; bj < 4; bj++) {
        fBh[bj] = &lds[4096 + (wc * 4 + bj) * 512 + laneoff];
        fBl[bj] = &lds[8192 + (wc * 4 + bj) * 512 + laneoff];
    }

    float xq[2][4];
    #pragma unroll
    for (int ai = 0; ai < 2; ai++)
        #pragma unroll
        for (int g = 0; g < 4; g++)
            xq[ai][g] = xsq[t0 + wr * 32 + ai * 16 + (l >> 4) * 4 + g];

    float m1[2][4], m2[2][4], m3[2][4];
    int   i1[2][4], i2[2][4];
    #pragma unroll
    for (int ai = 0; ai < 2; ai++)
        #pragma unroll
        for (int g = 0; g < 4; g++) {
            m1[ai][g] = INFINITY; m2[ai][g] = INFINITY; m3[ai][g] = INFINITY;
            i1[ai][g] = 0; i2[ai][g] = 0;
        }

    for (int ktile = 0; ktile < (KK / KSPLIT) / 128; ktile++) {
        const int koff = ktile * 128 * DD;
        f32x4 acc[2][4];
        #pragma unroll
        for (int ai = 0; ai < 2; ai++)
            #pragma unroll
            for (int bj = 0; bj < 4; bj++)
                acc[ai][bj] = (f32x4){0.f, 0.f, 0.f, 0.f};

        for (int step = 0; step < 8; step++) {
            const int d0 = step * 32;
            __syncthreads();           // previous step's fragment reads done
            GLOAD16(sAh + d0, dAh);
            GLOAD16(sAl + d0, dAl);
            GLOAD16(sB0h + koff + d0, dB0h);
            GLOAD16(sB1h + koff + d0, dB1h);
            GLOAD16(sB0l + koff + d0, dB0l);
            GLOAD16(sB1l + koff + d0, dB1l);
            __syncthreads();           // compiler drains vmcnt(0) before barrier

            bf16x8 ah0 = *(const bf16x8*)fAh[0];
            bf16x8 ah1 = *(const bf16x8*)fAh[1];
            bf16x8 al0 = *(const bf16x8*)fAl[0];
            bf16x8 al1 = *(const bf16x8*)fAl[1];
            #pragma unroll
            for (int bj = 0; bj < 4; bj++) {
                bf16x8 bh = *(const bf16x8*)fBh[bj];
                bf16x8 bl = *(const bf16x8*)fBl[bj];
                acc[0][bj] = __builtin_amdgcn_mfma_f32_16x16x32_bf16(al0, bh, acc[0][bj], 0, 0, 0);
                acc[0][bj] = __builtin_amdgcn_mfma_f32_16x16x32_bf16(ah0, bl, acc[0][bj], 0, 0, 0);
                acc[0][bj] = __builtin_amdgcn_mfma_f32_16x16x32_bf16(ah0, bh, acc[0][bj], 0, 0, 0);
                acc[1][bj] = __builtin_amdgcn_mfma_f32_16x16x32_bf16(al1, bh, acc[1][bj], 0, 0, 0);
                acc[1][bj] = __builtin_amdgcn_mfma_f32_16x16x32_bf16(ah1, bl, acc[1][bj], 0, 0, 0);
                acc[1][bj] = __builtin_amdgcn_mfma_f32_16x16x32_bf16(ah1, bh, acc[1][bj], 0, 0, 0);
            }
        }

        // epilogue: approx_t2 + top3 update. D: row=(l>>4)*4+g, col=l&15.
        const int cb0 = k0 + ktile * 128 + wc * 64 + (l & 15);
        float eq[4];
        #pragma unroll
        for (int bj = 0; bj < 4; bj++) eq[bj] = esq[cb0 + bj * 16];
        #pragma unroll
        for (int ai = 0; ai < 2; ai++)
            #pragma unroll
            for (int bj = 0; bj < 4; bj++) {
                #pragma unroll
                for (int g = 0; g < 4; g++) {
                    const float val = fmaf(-2.0f, acc[ai][bj][g], xq[ai][g]) + eq[bj];
                    const int code = cb0 + bj * 16;
                    const bool lt1 = val < m1[ai][g];
                    const bool lt2 = val < m2[ai][g];
                    const bool lt3 = val < m3[ai][g];
                    m3[ai][g] = lt2 ? m2[ai][g] : (lt3 ? val : m3[ai][g]);
                    m2[ai][g] = lt1 ? m1[ai][g] : (lt2 ? val : m2[ai][g]);
                    i2[ai][g] = lt1 ? i1[ai][g] : (lt2 ? code : i2[ai][g]);
                    m1[ai][g] = lt1 ? val : m1[ai][g];
                    i1[ai][g] = lt1 ? code : i1[ai][g];
                }
            }
    }

    // within-wave merge across the 16 code-columns
    float A1[2][4], A2[2][4], A3[2][4];
    int   B1[2][4], B2[2][4];
    #pragma unroll
    for (int ai = 0; ai < 2; ai++)
        #pragma unroll
        for (int g = 0; g < 4; g++) {
            float a1 = m1[ai][g], a2 = m2[ai][g], a3 = m3[ai][g];
            int b1 = i1[ai][g], b2 = i2[ai][g];
            #pragma unroll
            for (int off = 1; off < 16; off <<= 1) {
                float n1 = __shfl_xor(a1, off);
                int   j1 = __shfl_xor(b1, off);
                float n2 = __shfl_xor(a2, off);
                int   j2 = __shfl_xor(b2, off);
                float n3 = __shfl_xor(a3, off);
                comb(a1, b1, a2, b2, a3, n1, j1, n2, j2, n3);
            }
            A1[ai][g] = a1; B1[ai][g] = b1;
            A2[ai][g] = a2; B2[ai][g] = b2;
            A3[ai][g] = a3;
        }

    // cross-wave merge (ROUND-6 FIX): (wr,wc=0) and (wr,wc=1) cover disjoint
    // code halves of each 128-tile -> combine via LDS, then one writer.
    __syncthreads();                    // all fragment ds_reads complete
    float* const lsf = (float*)lds;
    int*   const lsi = (int*)lds;
    if (wc == 0 && (l & 15) == 0) {
        #pragma unroll
        for (int ai = 0; ai < 2; ai++)
            #pragma unroll
            for (int g = 0; g < 4; g++) {
                const int s = (wr * 32 + ai * 16 + (l >> 4) * 4 + g) * 5;
                lsf[s] = A1[ai][g];     lsi[s + 1] = B1[ai][g];
                lsf[s + 2] = A2[ai][g]; lsi[s + 3] = B2[ai][g];
                lsf[s + 4] = A3[ai][g];
            }
    }
    __syncthreads();
    if (wc == 1 && (l & 15) == 0) {
        #pragma unroll
        for (int ai = 0; ai < 2; ai++)
            #pragma unroll
            for (int g = 0; g < 4; g++) {
                const int s = (wr * 32 + ai * 16 + (l >> 4) * 4 + g) * 5;
                float a1 = A1[ai][g], a2 = A2[ai][g], a3 = A3[ai][g];
                int b1 = B1[ai][g], b2 = B2[ai][g];
                comb(a1, b1, a2, b2, a3,
                     lsf[s], lsi[s + 1], lsf[s + 2], lsi[s + 3], lsf[s + 4]);
                const int tok = t0 + wr * 32 + ai * 16 + (l >> 4) * 4 + g;
                const int o = split * TT + tok;
                sm1[o] = a1; si1[o] = b1; sm2[o] = a2; si2[o] = b2; sm3[o] = a3;
            }
    }
}

// exact t2 via the validated bit-exact chain (sequential ascending-d fmaf)
__device__ __forceinline__ float exact_t2(const float* __restrict__ x,
                                          const float* __restrict__ embed,
                                          const float* __restrict__ xsq,
                                          const float* __restrict__ esq,
                                          int t, int k) {
    const float* xp = x + (size_t)t * DD;
    const float* ep = embed + (size_t)k * DD;
    float acc = 0.0f;
    #pragma unroll 8
    for (int d = 0; d < DD; d++) acc = fmaf(xp[d], ep[d], acc);
    const float t1 = xsq[t] - 2.0f * acc;
    return t1 + esq[k];
}

// ---- kernel 3: resolve (classify / exact rescore / full rescan) + gather ----
__global__ __launch_bounds__(256)
void resolve_gather_kernel(const float* __restrict__ x, const float* __restrict__ embed,
                           const float* __restrict__ xsq, const float* __restrict__ esq,
                           const float* __restrict__ sm1, const int* __restrict__ si1,
                           const float* __restrict__ sm2, const int* __restrict__ si2,
                           const float* __restrict__ sm3,
                           float* __restrict__ quant, float* __restrict__ out_ind) {
    const int wave = threadIdx.x >> 6;
    const int l = threadIdx.x & 63;
    const int t = blockIdx.x * 4 + wave;

    // merge the two split states (comb tie-breaks by lower index)
    float a1 = sm1[t], a2 = sm2[t], a3 = sm3[t];
    int b1 = si1[t], b2 = si2[t];
    comb(a1, b1, a2, b2, a3, sm1[TT + t], si1[TT + t], sm2[TT + t], si2[TT + t], sm3[TT + t]);

    int winner;
    if (a2 > a1 + MU) {
        winner = b1;                      // provably the exact argmin
    } else if (a3 > a1 + MU) {
        // exactly-2 candidates: exact compare (ties -> lower index)
        const float e1 = exact_t2(x, embed, xsq, esq, t, b1);
        const float e2 = exact_t2(x, embed, xsq, esq, t, b2);
        winner = ((e2 < e1) || (e2 == e1 && b2 < b1)) ? b2 : b1;
    } else {
        // rare: full exact rescan over all K (lane l owns codes [l*64, l*64+64))
        const float* xp = x + (size_t)t * DD;
        const float xqv = xsq[t];
        float bv = INFINITY;
        int bi = 0;
        for (int cb = 0; cb < 64; cb += 4) {
            const int c0 = l * 64 + cb;
            const float* e0 = embed + (size_t)c0 * DD;
            float q0 = 0.f, q1 = 0.f, q2 = 0.f, q3 = 0.f;
            #pragma unroll 4
            for (int d = 0; d < DD; d++) {
                const float xv = xp[d];
                q0 = fmaf(xv, e0[d], q0);
                q1 = fmaf(xv, e0[DD + d], q1);
                q2 = fmaf(xv, e0[2 * DD + d], q2);
                q3 = fmaf(xv, e0[3 * DD + d], q3);
            }
            float tv;
            tv = (xqv - 2.0f * q0) + esq[c0 + 0]; if (tv < bv) { bv = tv; bi = c0 + 0; }
            tv = (xqv - 2.0f * q1) + esq[c0 + 1]; if (tv < bv) { bv = tv; bi = c0 + 1; }
            tv = (xqv - 2.0f * q2) + esq[c0 + 2]; if (tv < bv) { bv = tv; bi = c0 + 2; }
            tv = (xqv - 2.0f * q3) + esq[c0 + 3]; if (tv < bv) { bv = tv; bi = c0 + 3; }
        }
        #pragma unroll
        for (int off = 1; off < 64; off <<= 1) {
            const float ov = __shfl_xor(bv, off);
            const int   oi = __shfl_xor(bi, off);
            if (ov < bv || (ov == bv && oi < bi)) { bv = ov; bi = oi; }
        }
        winner = bi;
    }

    // gather quantize row + write index
    float4 v = reinterpret_cast<const float4*>(embed + (size_t)winner * DD)[l];
    reinterpret_cast<float4*>(quant + (size_t)t * DD)[l] = v;
    if (l == 0) out_ind[t] = (float)winner;
}

extern "C" void kernel_launch(void* const* d_in, const int* in_sizes, int n_in,
                              void* d_out, int out_size, void* d_ws, size_t ws_size,
                              hipStream_t stream) {
    const float* x     = (const float*)d_in[0];
    const float* embed = (const float*)d_in[1];
    // d_in[2] = node_mask: does not affect the two outputs.

    // ws layout (~5.4 MB)
    float* xsq = (float*)d_ws;                       // TT
    float* esq = xsq + TT;                           // KK
    short* e_hi = (short*)(esq + KK);                // KK*DD shorts
    short* e_lo = e_hi + (size_t)KK * DD;
    float* sm1 = (float*)(e_lo + (size_t)KK * DD);   // KSPLIT*TT each:
    int*   si1 = (int*)(sm1 + KSPLIT * TT);
    float* sm2 = (float*)(si1 + KSPLIT * TT);
    int*   si2 = (int*)(sm2 + KSPLIT * TT);
    float* sm3 = (float*)(si2 + KSPLIT * TT);

    // x planes live in d_out's quantize region (exactly TT*DD*4 bytes);
    // consumed by the screen, then overwritten by the final gather.
    short* x_hi = (short*)d_out;
    short* x_lo = x_hi + (size_t)TT * DD;

    float* quant   = (float*)d_out;
    float* out_ind = (float*)d_out + (size_t)TT * DD;

    prep_kernel<<<TT / 16, 256, 0, stream>>>(x, xsq, x_hi, x_lo);
    prep_kernel<<<KK / 16, 256, 0, stream>>>(embed, esq, e_hi, e_lo);
    screen_kernel<<<(TT / 64) * KSPLIT, 256, 0, stream>>>(x_hi, x_lo, e_hi, e_lo,
                                                          xsq, esq, sm1, si1, sm2, si2, sm3);
    resolve_gather_kernel<<<TT / 4, 256, 0, stream>>>(x, embed, xsq, esq,
                                                      sm1, si1, sm2, si2, sm3,
                                                      quant, out_ind);
}